// Round 5
// baseline (100.805 us; speedup 1.0000x reference)
//
#include <hip/hip_runtime.h>
#include <math.h>

// Problem constants
#define BATCH 2
#define SEQ   2048
#define DIM   1024
#define RANK  256
#define HEADS 16
#define HS    16
#define DH    64
#define MROWS 4096

#define QSCALE 0.36067376f   // 0.25 * log2(e), folded into normalized q

typedef __attribute__((ext_vector_type(8)))  short    short8;   // 8 bf16
typedef __attribute__((ext_vector_type(4)))  float    f32x4;
typedef __attribute__((ext_vector_type(16))) float    f32x16;
typedef __attribute__((ext_vector_type(2)))  unsigned uint2v;

__device__ __forceinline__ unsigned short f2bf(float f) {
    union { float f; unsigned u; } v; v.f = f;
    return (unsigned short)((v.u + 0x7FFFu + ((v.u >> 16) & 1u)) >> 16);  // RNE
}
__device__ __forceinline__ float bf2f(unsigned short h) {
    union { unsigned u; float f; } v; v.u = ((unsigned)h) << 16;
    return v.f;
}

// ---------------- fused f32 -> bf16 convert for x, Wqk, Wv (one launch) ----------------
#define XQ   1048576   // x quads (4096*1024/4)
#define WQKQ 131072    // Wqk quads
#define WVQ  262144    // Wv quads
__global__ __launch_bounds__(256) void conv3(const float* __restrict__ x,
                                             const float* __restrict__ wqk,
                                             const float* __restrict__ wv,
                                             unsigned short* __restrict__ xb,
                                             unsigned short* __restrict__ wcat)
{
    const int i = blockIdx.x * 256 + threadIdx.x;
    const float* src; unsigned short* dst; int j;
    if (i < XQ)              { src = x;   dst = xb;   j = i; }
    else if (i < XQ + WQKQ)  { src = wqk; dst = wcat; j = i - XQ; }
    else                     { src = wv;  dst = wcat + (size_t)4 * WQKQ; j = i - XQ - WQKQ; }
    float4 v = ((const float4*)src)[j];
    ushort4 o; o.x = f2bf(v.x); o.y = f2bf(v.y); o.z = f2bf(v.z); o.w = f2bf(v.w);
    ((ushort4*)dst)[j] = o;
}

// ---------------- MFMA GEMM, 128x64 tile ----------------
__global__ __launch_bounds__(256) void gemm_mfma(const unsigned short* __restrict__ A,
                                                 const unsigned short* __restrict__ W,
                                                 unsigned short* __restrict__ qkb,
                                                 unsigned short* __restrict__ vt)
{
    __shared__ __align__(16) unsigned short Alds[128 * 32];
    __shared__ __align__(16) unsigned short Blds[64 * 32];

    const int tid = threadIdx.x;
    const int w = tid >> 6, lane = tid & 63;
    const int lr = lane & 15, lg = lane >> 4;
    const int wm = w >> 1, wn = w & 1;
    const int bm = blockIdx.x * 128, bn = blockIdx.y * 64;

    const int srow = lane >> 2;
    const int sk   = (lane & 3) * 8;

    f32x4 acc[4][2] = {};

    for (int k0 = 0; k0 < 1024; k0 += 32) {
        __syncthreads();
        #pragma unroll
        for (int q = 0; q < 2; ++q) {
            const int r = (w * 2 + q) * 16 + srow;
            __builtin_amdgcn_global_load_lds(
                (const __attribute__((address_space(1))) unsigned int*)&A[(size_t)(bm + r) * 1024 + k0 + sk],
                (__attribute__((address_space(3))) unsigned int*)&Alds[(w * 2 + q) * 512],
                16, 0, 0);
        }
        __builtin_amdgcn_global_load_lds(
            (const __attribute__((address_space(1))) unsigned int*)&W[(size_t)(bn + w * 16 + srow) * 1024 + k0 + sk],
            (__attribute__((address_space(3))) unsigned int*)&Blds[w * 512],
            16, 0, 0);
        __syncthreads();

        short8 af[4], bfr[2];
        #pragma unroll
        for (int mi = 0; mi < 4; ++mi)
            af[mi] = *(const short8*)&Alds[(wm * 64 + mi * 16 + lr) * 32 + lg * 8];
        #pragma unroll
        for (int ni = 0; ni < 2; ++ni)
            bfr[ni] = *(const short8*)&Blds[(wn * 32 + ni * 16 + lr) * 32 + lg * 8];
        #pragma unroll
        for (int mi = 0; mi < 4; ++mi)
            #pragma unroll
            for (int ni = 0; ni < 2; ++ni)
                acc[mi][ni] = __builtin_amdgcn_mfma_f32_16x16x32_bf16(af[mi], bfr[ni], acc[mi][ni], 0, 0, 0);
    }

    if (bn < 512) {
        #pragma unroll
        for (int mi = 0; mi < 4; ++mi) {
            const int rbase = bm + wm * 64 + mi * 16 + lg * 4;
            #pragma unroll
            for (int ni = 0; ni < 2; ++ni) {
                const int col = bn + wn * 32 + ni * 16 + lr;
                #pragma unroll
                for (int r = 0; r < 4; ++r)
                    qkb[(size_t)(rbase + r) * 512 + col] = f2bf(acc[mi][ni][r]);
            }
        }
    } else {
        const int nb = bn - 512;
        #pragma unroll
        for (int mi = 0; mi < 4; ++mi) {
            const int m = bm + wm * 64 + mi * 16 + lg * 4;
            const int bb = m >> 11, ms = m & 2047;
            #pragma unroll
            for (int ni = 0; ni < 2; ++ni) {
                const int d = nb + wn * 32 + ni * 16 + lr;
                ushort4 pk;
                pk.x = f2bf(acc[mi][ni][0]); pk.y = f2bf(acc[mi][ni][1]);
                pk.z = f2bf(acc[mi][ni][2]); pk.w = f2bf(acc[mi][ni][3]);
                *(ushort4*)&vt[((size_t)bb * DIM + d) * SEQ + ms] = pk;
            }
        }
    }
}

// ---------------- Full-rank L2 normalize, split q/k; q pre-scaled by QSCALE ----------------
__global__ __launch_bounds__(256) void l2norm_split(const unsigned short* __restrict__ qkb,
                                                    unsigned short* __restrict__ qn,
                                                    unsigned short* __restrict__ kn)
{
    const int row = blockIdx.x;
    const int t = threadIdx.x;
    const unsigned short* p = qkb + (size_t)row * 512;
    float q = bf2f(p[t]);
    float k = bf2f(p[t + 256]);
    float sq = q * q, sk = k * k;
    #pragma unroll
    for (int off = 32; off > 0; off >>= 1) {
        sq += __shfl_down(sq, off);
        sk += __shfl_down(sk, off);
    }
    __shared__ float sh[8];
    const int wid = t >> 6;
    if ((t & 63) == 0) { sh[wid * 2] = sq; sh[wid * 2 + 1] = sk; }
    __syncthreads();
    sq = sh[0] + sh[2] + sh[4] + sh[6];
    sk = sh[1] + sh[3] + sh[5] + sh[7];
    const float rq = QSCALE / fmaxf(sqrtf(sq), 1e-6f);   // fold softmax scale into q
    const float rk = 1.0f   / fmaxf(sqrtf(sk), 1e-6f);
    qn[(size_t)row * 256 + t] = f2bf(q * rq);
    kn[(size_t)row * 256 + t] = f2bf(k * rk);
}

// ---------------- 32x32 MFMA flash attention: 1 q-band x 4 key-split waves ----------------
// Block = 32 q-rows, 4 waves each owning 32 keys of every 128-key tile.
// No-max softmax (scores in [-0.361,0.361] after QSCALE fold) -> exp2 direct,
// partials across kh-waves simply add (merged in-block at epilogue).
// V single-buffered in LDS (16KB, XOR-swizzled via pre-swizzled global source);
// K fragments loaded global->reg with one-tile prefetch.

template<bool MASK>
__device__ __forceinline__ void tile_compute(int keybase, int qband, int l31, int hi, int kh,
                                             const short8 ak, const short8 bq,
                                             const unsigned short* Vs,
                                             f32x16 o[2], float& lpa, float& lpb)
{
    const f32x16 z = {};
    f32x16 sp = __builtin_amdgcn_mfma_f32_32x32x16_bf16(ak, bq, z, 0, 0, 0);

    #pragma unroll
    for (int r = 0; r < 16; ++r) {
        float e = __builtin_exp2f(sp[r]);
        if (MASK) {
            const int key = keybase + (r & 3) + 8 * (r >> 2) + 4 * hi;
            e = (key > qband + l31) ? 0.0f : e;
        }
        sp[r] = e;
        if (r & 1) lpb += e; else lpa += e;
    }

    // rebuild PV A-frags in-register: slice g needs keys 16g + 8hi + e
    short8 pa[2];
    #pragma unroll
    for (int g = 0; g < 2; ++g) {
        const int jj = 2 * g;
        unsigned a0, a1, b0, b1;
        asm("v_cvt_pk_bf16_f32 %0, %1, %2" : "=v"(a0) : "v"(sp[4*jj]),     "v"(sp[4*jj + 1]));
        asm("v_cvt_pk_bf16_f32 %0, %1, %2" : "=v"(b0) : "v"(sp[4*jj + 2]), "v"(sp[4*jj + 3]));
        asm("v_cvt_pk_bf16_f32 %0, %1, %2" : "=v"(a1) : "v"(sp[4*jj + 4]), "v"(sp[4*jj + 5]));
        asm("v_cvt_pk_bf16_f32 %0, %1, %2" : "=v"(b1) : "v"(sp[4*jj + 6]), "v"(sp[4*jj + 7]));
        const uint2v r0 = __builtin_amdgcn_permlane32_swap(a0, a1, false, false);
        const uint2v r1 = __builtin_amdgcn_permlane32_swap(b0, b1, false, false);
        union { short8 s; unsigned u[4]; } pu;
        pu.u[0] = r0[0]; pu.u[1] = r1[0]; pu.u[2] = r0[1]; pu.u[3] = r1[1];
        pa[g] = pu.s;
    }

    // PV: O[q][dh] += P[q][key] * V[key][dh]; V LDS is [dh][key], XOR-swizzled
    #pragma unroll
    for (int g = 0; g < 2; ++g)
        #pragma unroll
        for (int half = 0; half < 2; ++half) {
            const int row = 32 * half + l31;
            const int slot = (4 * kh + 2 * g + hi) ^ (row & 7);
            const short8 bv = *(const short8*)&Vs[row * 128 + 8 * slot];
            o[half] = __builtin_amdgcn_mfma_f32_32x32x16_bf16(pa[g], bv, o[half], 0, 0, 0);
        }
}

__global__ __launch_bounds__(256, 6) void attn32(const unsigned short* __restrict__ qn,
                                                 const unsigned short* __restrict__ kn,
                                                 const unsigned short* __restrict__ vt,
                                                 float* __restrict__ out)
{
    const int qt = (int)gridDim.x - 1 - (int)blockIdx.x;  // LPT: heavy first
    const int h = blockIdx.y, b = blockIdx.z;
    const int tid = threadIdx.x, kh = tid >> 6, lane = tid & 63;
    const int l31 = lane & 31, hi = lane >> 5;
    const int qband = qt * 32;

    __shared__ __align__(16) unsigned char smem[16384 + 1024];  // V 16K | Ls 1K
    unsigned short* Vs = (unsigned short*)smem;
    float* Ls = (float*)(smem + 16384);

    // Q B-frag (pre-scaled): col = q (l31), feats 8hi..+7
    const short8 bq = *(const short8*)&qn[((size_t)b * SEQ + qband + l31) * RANK + h * HS + 8 * hi];

    f32x16 o[2] = {};
    float lpa = 0.0f, lpb = 0.0f;

    const int nt = (qt + 4) >> 2;   // ceil((qt+1)/4) tiles of 128 keys

    // K A-frag pointer (global->reg, one-tile prefetch)
    const unsigned short* kp = kn + ((size_t)b * SEQ + 32 * kh + l31) * RANK + h * HS + 8 * hi;
    short8 ak = *(const short8*)kp;

    // V staging geometry: sweep i, wave kh -> rows i*16 + kh*4 + (lane>>4)
    const int vrow_s = kh * 4 + (lane >> 4);
    const int vslot  = lane & 15;

    for (int t = 0; t < nt; ++t) {
        __syncthreads();   // [A] all waves done reading V(t-1)
        {
            const int k0 = t * 128;
            #pragma unroll
            for (int i = 0; i < 4; ++i) {
                const int row = i * 16 + vrow_s;
                const int so  = 8 * (vslot ^ (row & 7));   // pre-swizzled source col
                __builtin_amdgcn_global_load_lds(
                    (const __attribute__((address_space(1))) unsigned int*)
                        &vt[((size_t)b * DIM + h * DH + row) * SEQ + k0 + so],
                    (__attribute__((address_space(3))) unsigned int*)(smem + i * 4096 + kh * 1024),
                    16, 0, 0);
            }
        }
        __syncthreads();   // [B] vmcnt(0) drain + cross-wave visibility

        short8 ak_nxt = ak;
        if (t + 1 < nt) ak_nxt = *(const short8*)(kp + (size_t)(t + 1) * 128 * RANK);

        const int keybase = t * 128 + 32 * kh;
        __builtin_amdgcn_s_setprio(1);
        if (keybase <= qband + 31) {
            if (keybase + 31 <= qband)
                tile_compute<false>(keybase, qband, l31, hi, kh, ak, bq, Vs, o, lpa, lpb);
            else
                tile_compute<true>(keybase, qband, l31, hi, kh, ak, bq, Vs, o, lpa, lpb);
        }
        __builtin_amdgcn_s_setprio(0);
        ak = ak_nxt;
    }

    // ---- epilogue: merge 4 kh-partials, normalize, store ----
    float lp = lpa + lpb;
    lp += __shfl_xor(lp, 32);

    __syncthreads();                       // E0: V dead, reuse smem
    float* Os = (float*)smem;              // 2 slots x [32 rr][64 lanes]
    Ls[kh * 64 + lane] = lp;
    if (kh >= 2) {
        #pragma unroll
        for (int half = 0; half < 2; ++half)
            #pragma unroll
            for (int r = 0; r < 16; ++r)
                Os[(kh - 2) * 2048 + (half * 16 + r) * 64 + lane] = o[half][r];
    }
    __syncthreads();                       // E1
    if (kh < 2) {
        #pragma unroll
        for (int half = 0; half < 2; ++half)
            #pragma unroll
            for (int r = 0; r < 16; ++r)
                o[half][r] += Os[kh * 2048 + (half * 16 + r) * 64 + lane];
    }
    __syncthreads();                       // E2
    if (kh == 1) {
        #pragma unroll
        for (int half = 0; half < 2; ++half)
            #pragma unroll
            for (int r = 0; r < 16; ++r)
                Os[(half * 16 + r) * 64 + lane] = o[half][r];
    }
    __syncthreads();                       // E3
    if (kh == 0) {
        const float lt = Ls[lane] + Ls[64 + lane] + Ls[128 + lane] + Ls[192 + lane];
        const float inv = 1.0f / fmaxf(lt, 1e-6f);
        #pragma unroll
        for (int half = 0; half < 2; ++half)
            #pragma unroll
            for (int r = 0; r < 16; ++r) {
                const int q = (r & 3) + 8 * (r >> 2) + 4 * hi;
                const float iv = __shfl(inv, q);
                const float val = (o[half][r] + Os[(half * 16 + r) * 64 + lane]) * iv;
                out[((size_t)b * SEQ + qband + q) * DIM + h * DH + half * 32 + l31] = val;
            }
    }
}

extern "C" void kernel_launch(void* const* d_in, const int* in_sizes, int n_in,
                              void* d_out, int out_size, void* d_ws, size_t ws_size,
                              hipStream_t stream)
{
    const float* x   = (const float*)d_in[0];
    // d_in[1] = mask (causal, analytic)
    const float* Wqk = (const float*)d_in[2];
    const float* Wv  = (const float*)d_in[3];
    float* out = (float*)d_out;

    // workspace: xb 8MB | qkb 4MB | vt 8MB | wcat 3MB ; qn/kn overlay xb after GEMM
    unsigned short* xb   = (unsigned short*)d_ws;
    unsigned short* qkb  = xb  + (size_t)MROWS * DIM;
    unsigned short* vt   = qkb + (size_t)MROWS * 512;
    unsigned short* wcat = vt  + (size_t)BATCH * DIM * SEQ;
    unsigned short* qn = xb;
    unsigned short* kn = xb + (size_t)MROWS * RANK;

    conv3<<<5632, 256, 0, stream>>>(x, Wqk, Wv, xb, wcat);
    gemm_mfma<<<dim3(32, 24), 256, 0, stream>>>(xb, wcat, qkb, vt);
    l2norm_split<<<MROWS, 256, 0, stream>>>(qkb, qn, kn);
    attn32<<<dim3(SEQ / 32, HEADS, BATCH), 256, 0, stream>>>(qn, kn, vt, out);
}

// Round 6
// 79.489 us; speedup vs baseline: 1.2682x; 1.2682x over previous
//
#include <hip/hip_runtime.h>
#include <math.h>

// Problem constants
#define BATCH 2
#define SEQ   2048
#define DIM   1024
#define RANK  256
#define HEADS 16
#define HS    16
#define DH    64
#define MROWS 4096

#define QSCALE 0.36067376f   // 0.25 * log2(e), folded into normalized q

typedef __attribute__((ext_vector_type(8)))  short    short8;   // 8 bf16
typedef __attribute__((ext_vector_type(4)))  float    f32x4;
typedef __attribute__((ext_vector_type(16))) float    f32x16;
typedef __attribute__((ext_vector_type(2)))  unsigned uint2v;

__device__ __forceinline__ unsigned short f2bf(float f) {
    union { float f; unsigned u; } v; v.f = f;
    return (unsigned short)((v.u + 0x7FFFu + ((v.u >> 16) & 1u)) >> 16);  // RNE
}
__device__ __forceinline__ float bf2f(unsigned short h) {
    union { unsigned u; float f; } v; v.u = ((unsigned)h) << 16;
    return v.f;
}

// ---------------- fused f32 -> bf16 convert for x, Wqk, Wv ----------------
#define XQ   1048576
#define WQKQ 131072
#define WVQ  262144
__global__ __launch_bounds__(256) void conv3(const float* __restrict__ x,
                                             const float* __restrict__ wqk,
                                             const float* __restrict__ wv,
                                             unsigned short* __restrict__ xb,
                                             unsigned short* __restrict__ wcat)
{
    const int i = blockIdx.x * 256 + threadIdx.x;
    const float* src; unsigned short* dst; int j;
    if (i < XQ)              { src = x;   dst = xb;   j = i; }
    else if (i < XQ + WQKQ)  { src = wqk; dst = wcat; j = i - XQ; }
    else                     { src = wv;  dst = wcat + (size_t)4 * WQKQ; j = i - XQ - WQKQ; }
    float4 v = ((const float4*)src)[j];
    ushort4 o; o.x = f2bf(v.x); o.y = f2bf(v.y); o.z = f2bf(v.z); o.w = f2bf(v.w);
    ((ushort4*)dst)[j] = o;
}

// ---------------- MFMA GEMM, 128x64 tile ----------------
__global__ __launch_bounds__(256) void gemm_mfma(const unsigned short* __restrict__ A,
                                                 const unsigned short* __restrict__ W,
                                                 unsigned short* __restrict__ qkb,
                                                 unsigned short* __restrict__ vt)
{
    __shared__ __align__(16) unsigned short Alds[128 * 32];
    __shared__ __align__(16) unsigned short Blds[64 * 32];

    const int tid = threadIdx.x;
    const int w = tid >> 6, lane = tid & 63;
    const int lr = lane & 15, lg = lane >> 4;
    const int wm = w >> 1, wn = w & 1;
    const int bm = blockIdx.x * 128, bn = blockIdx.y * 64;

    const int srow = lane >> 2;
    const int sk   = (lane & 3) * 8;

    f32x4 acc[4][2] = {};

    for (int k0 = 0; k0 < 1024; k0 += 32) {
        __syncthreads();
        #pragma unroll
        for (int q = 0; q < 2; ++q) {
            const int r = (w * 2 + q) * 16 + srow;
            __builtin_amdgcn_global_load_lds(
                (const __attribute__((address_space(1))) unsigned int*)&A[(size_t)(bm + r) * 1024 + k0 + sk],
                (__attribute__((address_space(3))) unsigned int*)&Alds[(w * 2 + q) * 512],
                16, 0, 0);
        }
        __builtin_amdgcn_global_load_lds(
            (const __attribute__((address_space(1))) unsigned int*)&W[(size_t)(bn + w * 16 + srow) * 1024 + k0 + sk],
            (__attribute__((address_space(3))) unsigned int*)&Blds[w * 512],
            16, 0, 0);
        __syncthreads();

        short8 af[4], bfr[2];
        #pragma unroll
        for (int mi = 0; mi < 4; ++mi)
            af[mi] = *(const short8*)&Alds[(wm * 64 + mi * 16 + lr) * 32 + lg * 8];
        #pragma unroll
        for (int ni = 0; ni < 2; ++ni)
            bfr[ni] = *(const short8*)&Blds[(wn * 32 + ni * 16 + lr) * 32 + lg * 8];
        #pragma unroll
        for (int mi = 0; mi < 4; ++mi)
            #pragma unroll
            for (int ni = 0; ni < 2; ++ni)
                acc[mi][ni] = __builtin_amdgcn_mfma_f32_16x16x32_bf16(af[mi], bfr[ni], acc[mi][ni], 0, 0, 0);
    }

    if (bn < 512) {
        #pragma unroll
        for (int mi = 0; mi < 4; ++mi) {
            const int rbase = bm + wm * 64 + mi * 16 + lg * 4;
            #pragma unroll
            for (int ni = 0; ni < 2; ++ni) {
                const int col = bn + wn * 32 + ni * 16 + lr;
                #pragma unroll
                for (int r = 0; r < 4; ++r)
                    qkb[(size_t)(rbase + r) * 512 + col] = f2bf(acc[mi][ni][r]);
            }
        }
    } else {
        const int nb = bn - 512;
        #pragma unroll
        for (int mi = 0; mi < 4; ++mi) {
            const int m = bm + wm * 64 + mi * 16 + lg * 4;
            const int bb = m >> 11, ms = m & 2047;
            #pragma unroll
            for (int ni = 0; ni < 2; ++ni) {
                const int d = nb + wn * 32 + ni * 16 + lr;
                ushort4 pk;
                pk.x = f2bf(acc[mi][ni][0]); pk.y = f2bf(acc[mi][ni][1]);
                pk.z = f2bf(acc[mi][ni][2]); pk.w = f2bf(acc[mi][ni][3]);
                *(ushort4*)&vt[((size_t)bb * DIM + d) * SEQ + ms] = pk;
            }
        }
    }
}

// ---------------- Full-rank L2 normalize; q pre-scaled by QSCALE ----------------
__global__ __launch_bounds__(256) void l2norm_split(const unsigned short* __restrict__ qkb,
                                                    unsigned short* __restrict__ qn,
                                                    unsigned short* __restrict__ kn)
{
    const int row = blockIdx.x;
    const int t = threadIdx.x;
    const unsigned short* p = qkb + (size_t)row * 512;
    float q = bf2f(p[t]);
    float k = bf2f(p[t + 256]);
    float sq = q * q, sk = k * k;
    #pragma unroll
    for (int off = 32; off > 0; off >>= 1) {
        sq += __shfl_down(sq, off);
        sk += __shfl_down(sk, off);
    }
    __shared__ float sh[8];
    const int wid = t >> 6;
    if ((t & 63) == 0) { sh[wid * 2] = sq; sh[wid * 2 + 1] = sk; }
    __syncthreads();
    sq = sh[0] + sh[2] + sh[4] + sh[6];
    sk = sh[1] + sh[3] + sh[5] + sh[7];
    const float rq = QSCALE / fmaxf(sqrtf(sq), 1e-6f);
    const float rk = 1.0f   / fmaxf(sqrtf(sk), 1e-6f);
    qn[(size_t)row * 256 + t] = f2bf(q * rq);
    kn[(size_t)row * 256 + t] = f2bf(k * rk);
}

// ---------------- 32x32 MFMA flash attention (R4 structure + XCD pinning) ----------------
// Block = 64 q-rows: 4 waves = 2 q-bands(32) x 2 k-halves(64 of a 128-key tile).
// Flat grid, bh = L&31, qt = 31-(L>>5): all 32 q-tiles of a (b,h) hit ONE XCD
// (L%8 == bh%8) -> V slice (256KB) + K slice (64KB) stay L2-resident.
// V double-buffered in LDS (XOR-swizzled via pre-swizzled global source);
// K A-frags global->reg with one-tile prefetch. No-max softmax, exp2 direct.

template<bool MASK>
__device__ __forceinline__ void tile32(const unsigned short* Vs, int keybase, int kh,
                                       int l31, int hi, int qg,
                                       const short8 ak0, const short8 ak1, const short8 bq,
                                       f32x16 o[2], float& lpart)
{
    const f32x16 z = {};
    const f32x16 s0 = __builtin_amdgcn_mfma_f32_32x32x16_bf16(ak0, bq, z, 0, 0, 0);
    const f32x16 s1 = __builtin_amdgcn_mfma_f32_32x32x16_bf16(ak1, bq, z, 0, 0, 0);

    float p0[16], p1[16];
    #pragma unroll
    for (int r = 0; r < 16; ++r) {
        float e0 = __builtin_exp2f(s0[r]);
        float e1 = __builtin_exp2f(s1[r]);
        if (MASK) {
            const int kl = keybase + (r & 3) + 8 * (r >> 2) + 4 * hi;
            e0 = (kl > qg) ? 0.0f : e0;
            e1 = (kl + 32 > qg) ? 0.0f : e1;
        }
        p0[r] = e0; p1[r] = e1;
        lpart += e0 + e1;
    }

    // rebuild PV A-frags: slice g needs keys 16g + 8hi + e (within the 64-key half)
    short8 pa[4];
    #pragma unroll
    for (int g = 0; g < 4; ++g) {
        const float* pc = (g < 2) ? p0 : p1;
        const int jj = 2 * (g & 1);
        unsigned a0, a1, b0, b1;
        asm("v_cvt_pk_bf16_f32 %0, %1, %2" : "=v"(a0) : "v"(pc[4*jj]),     "v"(pc[4*jj + 1]));
        asm("v_cvt_pk_bf16_f32 %0, %1, %2" : "=v"(b0) : "v"(pc[4*jj + 2]), "v"(pc[4*jj + 3]));
        asm("v_cvt_pk_bf16_f32 %0, %1, %2" : "=v"(a1) : "v"(pc[4*jj + 4]), "v"(pc[4*jj + 5]));
        asm("v_cvt_pk_bf16_f32 %0, %1, %2" : "=v"(b1) : "v"(pc[4*jj + 6]), "v"(pc[4*jj + 7]));
        const uint2v r0 = __builtin_amdgcn_permlane32_swap(a0, a1, false, false);
        const uint2v r1 = __builtin_amdgcn_permlane32_swap(b0, b1, false, false);
        union { short8 s; unsigned u[4]; } pu;
        pu.u[0] = r0[0]; pu.u[1] = r1[0]; pu.u[2] = r0[1]; pu.u[3] = r1[1];
        pa[g] = pu.s;
    }

    // PV: O[q][dh] += P * V ; Vs is [dh][key] (XOR-swizzled cols)
    #pragma unroll
    for (int g = 0; g < 4; ++g)
        #pragma unroll
        for (int half = 0; half < 2; ++half) {
            const int row = half * 32 + l31;
            const short8 bv = *(const short8*)&Vs[row * 128 + ((64 * kh + 16 * g + 8 * hi) ^ (8 * (row & 7)))];
            o[half] = __builtin_amdgcn_mfma_f32_32x32x16_bf16(pa[g], bv, o[half], 0, 0, 0);
        }
}

__global__ __launch_bounds__(256, 5) void attn64(const unsigned short* __restrict__ qn,
                                                 const unsigned short* __restrict__ kn,
                                                 const unsigned short* __restrict__ vt,
                                                 float* __restrict__ out)
{
    const int L = blockIdx.x;            // 1024 flat
    const int bh = L & 31;               // L%8 == bh%8 -> XCD-pinned per (b,h)
    const int qt = 31 - (L >> 5);        // heavy-first (LPT)
    const int h = bh & 15, b = bh >> 4;

    const int tid = threadIdx.x, w = tid >> 6, lane = tid & 63;
    const int qh = w >> 1, kh = w & 1;
    const int l31 = lane & 31, hi = lane >> 5;
    const int qband = qt * 64 + qh * 32;
    const int qg = qband + l31;

    __shared__ __align__(16) unsigned char smem[32768];  // V dbuf 2x16KB; epilogue overlay

    // Q B-frag (pre-scaled): col = q (l31), feats 8hi..+7
    const short8 bq = *(const short8*)&qn[((size_t)b * SEQ + qg) * RANK + h * HS + 8 * hi];

    f32x16 o[2] = {};
    float lpart = 0.0f;

    // K A-frag base (global->reg): rows 64*kh + l31 (+32), feats 8hi..+7
    const unsigned short* kbase = kn + ((size_t)b * SEQ + 64 * kh + l31) * RANK + h * HS + 8 * hi;
    short8 ak0 = *(const short8*)kbase;
    short8 ak1 = *(const short8*)(kbase + 32 * RANK);

    // V staging geometry: wave w stages dh rows w*16 + i*4 + (lane>>4)
    const int vsub  = lane >> 4;
    const int vslot = lane & 15;

#define STAGEV(kt_, buf_) do {                                                                    \
        const int k0_ = (kt_) * 128;                                                              \
        _Pragma("unroll")                                                                         \
        for (int i = 0; i < 4; ++i) {                                                             \
            const int dh = w * 16 + i * 4 + vsub;                                                 \
            const int so = 8 * (vslot ^ (dh & 7));                                                \
            __builtin_amdgcn_global_load_lds(                                                     \
                (const __attribute__((address_space(1))) unsigned int*)                           \
                    &vt[((size_t)b * DIM + h * DH + dh) * SEQ + k0_ + so],                        \
                (__attribute__((address_space(3))) unsigned int*)(smem + (buf_) * 16384 + (w * 4 + i) * 1024), \
                16, 0, 0);                                                                        \
        }                                                                                         \
    } while (0)

    const int ntiles = (qt >> 1) + 1;   // tiles of 128 keys

    STAGEV(0, 0);
    __syncthreads();

    for (int kt = 0; kt < ntiles - 1; ++kt) {
        STAGEV(kt + 1, (kt + 1) & 1);
        short8 an0 = *(const short8*)(kbase + (size_t)(kt + 1) * 128 * RANK);
        short8 an1 = *(const short8*)(kbase + (size_t)(kt + 1) * 128 * RANK + 32 * RANK);
        __builtin_amdgcn_s_setprio(1);
        tile32<false>((const unsigned short*)(smem + (kt & 1) * 16384),
                      kt * 128 + 64 * kh, kh, l31, hi, qg, ak0, ak1, bq, o, lpart);
        __builtin_amdgcn_s_setprio(0);
        ak0 = an0; ak1 = an1;
        __syncthreads();   // drains staging vmcnt + all waves past reads of old buf
    }
    {
        const int kt = ntiles - 1;
        const int wfirst = 128 * kt + 64 * kh;
        const unsigned short* Vs = (const unsigned short*)(smem + (kt & 1) * 16384);
        __builtin_amdgcn_s_setprio(1);
        if (wfirst <= qband + 31) {
            if (wfirst + 63 <= qband)
                tile32<false>(Vs, wfirst, kh, l31, hi, qg, ak0, ak1, bq, o, lpart);
            else
                tile32<true>(Vs, wfirst, kh, l31, hi, qg, ak0, ak1, bq, o, lpart);
        }
        __builtin_amdgcn_s_setprio(0);
    }
#undef STAGEV
    __syncthreads();   // V dead; reuse smem for merge

    float* Osm = (float*)smem;              // [2 bands][32 q][64 lane]
    float* Lsm = (float*)(smem + 16384);    // [2 bands][64 lane]
    if (kh == 1) {
        #pragma unroll
        for (int half = 0; half < 2; ++half)
            #pragma unroll
            for (int r = 0; r < 16; ++r) {
                const int q = (r & 3) + 8 * (r >> 2) + 4 * hi;
                Osm[(qh * 32 + q) * 64 + half * 32 + l31] = o[half][r];
            }
        Lsm[qh * 64 + lane] = lpart;
    }
    __syncthreads();
    if (kh == 0) {
        float lt = lpart + Lsm[qh * 64 + lane];
        lt += __shfl_xor(lt, 32);
        const float inv = 1.0f / fmaxf(lt, 1e-6f);
        #pragma unroll
        for (int r = 0; r < 16; ++r) {
            const int q = (r & 3) + 8 * (r >> 2) + 4 * hi;
            const float iv = __shfl(inv, q);
            #pragma unroll
            for (int half = 0; half < 2; ++half) {
                const float val = (o[half][r] + Osm[(qh * 32 + q) * 64 + half * 32 + l31]) * iv;
                out[((size_t)b * SEQ + qband + q) * DIM + h * DH + half * 32 + l31] = val;
            }
        }
    }
}

extern "C" void kernel_launch(void* const* d_in, const int* in_sizes, int n_in,
                              void* d_out, int out_size, void* d_ws, size_t ws_size,
                              hipStream_t stream)
{
    const float* x   = (const float*)d_in[0];
    // d_in[1] = mask (causal, analytic)
    const float* Wqk = (const float*)d_in[2];
    const float* Wv  = (const float*)d_in[3];
    float* out = (float*)d_out;

    // workspace: xb 8MB | qkb 4MB | vt 8MB | wcat 3MB ; qn/kn overlay xb after GEMM
    unsigned short* xb   = (unsigned short*)d_ws;
    unsigned short* qkb  = xb  + (size_t)MROWS * DIM;
    unsigned short* vt   = qkb + (size_t)MROWS * 512;
    unsigned short* wcat = vt  + (size_t)BATCH * DIM * SEQ;
    unsigned short* qn = xb;
    unsigned short* kn = xb + (size_t)MROWS * RANK;

    conv3<<<5632, 256, 0, stream>>>(x, Wqk, Wv, xb, wcat);
    gemm_mfma<<<dim3(32, 24), 256, 0, stream>>>(xb, wcat, qkb, vt);
    l2norm_split<<<MROWS, 256, 0, stream>>>(qkb, qn, kn);
    attn64<<<dim3(1024), 256, 0, stream>>>(qn, kn, vt, out);
}

// Round 7
// 73.467 us; speedup vs baseline: 1.3721x; 1.0820x over previous
//
#include <hip/hip_runtime.h>
#include <math.h>

// Problem constants
#define BATCH 2
#define SEQ   2048
#define DIM   1024
#define RANK  256
#define HEADS 16
#define HS    16
#define DH    64
#define MROWS 4096

#define QSCALE 0.36067376f   // 0.25 * log2(e), folded into normalized q

typedef __attribute__((ext_vector_type(8)))  short    short8;   // 8 bf16
typedef __attribute__((ext_vector_type(4)))  float    f32x4;
typedef __attribute__((ext_vector_type(16))) float    f32x16;
typedef __attribute__((ext_vector_type(2)))  unsigned uint2v;

__device__ __forceinline__ unsigned short f2bf(float f) {
    union { float f; unsigned u; } v; v.f = f;
    return (unsigned short)((v.u + 0x7FFFu + ((v.u >> 16) & 1u)) >> 16);  // RNE
}
__device__ __forceinline__ float bf2f(unsigned short h) {
    union { unsigned u; float f; } v; v.u = ((unsigned)h) << 16;
    return v.f;
}

// ---------------- fused f32 -> bf16 convert for x, Wqk, Wv ----------------
#define XQ   1048576
#define WQKQ 131072
#define WVQ  262144
__global__ __launch_bounds__(256) void conv3(const float* __restrict__ x,
                                             const float* __restrict__ wqk,
                                             const float* __restrict__ wv,
                                             unsigned short* __restrict__ xb,
                                             unsigned short* __restrict__ wcat)
{
    const int i = blockIdx.x * 256 + threadIdx.x;
    const float* src; unsigned short* dst; int j;
    if (i < XQ)              { src = x;   dst = xb;   j = i; }
    else if (i < XQ + WQKQ)  { src = wqk; dst = wcat; j = i - XQ; }
    else                     { src = wv;  dst = wcat + (size_t)4 * WQKQ; j = i - XQ - WQKQ; }
    float4 v = ((const float4*)src)[j];
    ushort4 o; o.x = f2bf(v.x); o.y = f2bf(v.y); o.z = f2bf(v.z); o.w = f2bf(v.w);
    ((ushort4*)dst)[j] = o;
}

// ---------------- MFMA GEMM, 128x64 tile ----------------
__global__ __launch_bounds__(256) void gemm_mfma(const unsigned short* __restrict__ A,
                                                 const unsigned short* __restrict__ W,
                                                 unsigned short* __restrict__ qkb,
                                                 unsigned short* __restrict__ vt)
{
    __shared__ __align__(16) unsigned short Alds[128 * 32];
    __shared__ __align__(16) unsigned short Blds[64 * 32];

    const int tid = threadIdx.x;
    const int w = tid >> 6, lane = tid & 63;
    const int lr = lane & 15, lg = lane >> 4;
    const int wm = w >> 1, wn = w & 1;
    const int bm = blockIdx.x * 128, bn = blockIdx.y * 64;

    const int srow = lane >> 2;
    const int sk   = (lane & 3) * 8;

    f32x4 acc[4][2] = {};

    for (int k0 = 0; k0 < 1024; k0 += 32) {
        __syncthreads();
        #pragma unroll
        for (int q = 0; q < 2; ++q) {
            const int r = (w * 2 + q) * 16 + srow;
            __builtin_amdgcn_global_load_lds(
                (const __attribute__((address_space(1))) unsigned int*)&A[(size_t)(bm + r) * 1024 + k0 + sk],
                (__attribute__((address_space(3))) unsigned int*)&Alds[(w * 2 + q) * 512],
                16, 0, 0);
        }
        __builtin_amdgcn_global_load_lds(
            (const __attribute__((address_space(1))) unsigned int*)&W[(size_t)(bn + w * 16 + srow) * 1024 + k0 + sk],
            (__attribute__((address_space(3))) unsigned int*)&Blds[w * 512],
            16, 0, 0);
        __syncthreads();

        short8 af[4], bfr[2];
        #pragma unroll
        for (int mi = 0; mi < 4; ++mi)
            af[mi] = *(const short8*)&Alds[(wm * 64 + mi * 16 + lr) * 32 + lg * 8];
        #pragma unroll
        for (int ni = 0; ni < 2; ++ni)
            bfr[ni] = *(const short8*)&Blds[(wn * 32 + ni * 16 + lr) * 32 + lg * 8];
        #pragma unroll
        for (int mi = 0; mi < 4; ++mi)
            #pragma unroll
            for (int ni = 0; ni < 2; ++ni)
                acc[mi][ni] = __builtin_amdgcn_mfma_f32_16x16x32_bf16(af[mi], bfr[ni], acc[mi][ni], 0, 0, 0);
    }

    if (bn < 512) {
        #pragma unroll
        for (int mi = 0; mi < 4; ++mi) {
            const int rbase = bm + wm * 64 + mi * 16 + lg * 4;
            #pragma unroll
            for (int ni = 0; ni < 2; ++ni) {
                const int col = bn + wn * 32 + ni * 16 + lr;
                #pragma unroll
                for (int r = 0; r < 4; ++r)
                    qkb[(size_t)(rbase + r) * 512 + col] = f2bf(acc[mi][ni][r]);
            }
        }
    } else {
        const int nb = bn - 512;
        #pragma unroll
        for (int mi = 0; mi < 4; ++mi) {
            const int m = bm + wm * 64 + mi * 16 + lg * 4;
            const int bb = m >> 11, ms = m & 2047;
            #pragma unroll
            for (int ni = 0; ni < 2; ++ni) {
                const int d = nb + wn * 32 + ni * 16 + lr;
                ushort4 pk;
                pk.x = f2bf(acc[mi][ni][0]); pk.y = f2bf(acc[mi][ni][1]);
                pk.z = f2bf(acc[mi][ni][2]); pk.w = f2bf(acc[mi][ni][3]);
                *(ushort4*)&vt[((size_t)bb * DIM + d) * SEQ + ms] = pk;
            }
        }
    }
}

// ---------------- Full-rank L2 normalize; q pre-scaled by QSCALE ----------------
__global__ __launch_bounds__(256) void l2norm_split(const unsigned short* __restrict__ qkb,
                                                    unsigned short* __restrict__ qn,
                                                    unsigned short* __restrict__ kn)
{
    const int row = blockIdx.x;
    const int t = threadIdx.x;
    const unsigned short* p = qkb + (size_t)row * 512;
    float q = bf2f(p[t]);
    float k = bf2f(p[t + 256]);
    float sq = q * q, sk = k * k;
    #pragma unroll
    for (int off = 32; off > 0; off >>= 1) {
        sq += __shfl_down(sq, off);
        sk += __shfl_down(sk, off);
    }
    __shared__ float sh[8];
    const int wid = t >> 6;
    if ((t & 63) == 0) { sh[wid * 2] = sq; sh[wid * 2 + 1] = sk; }
    __syncthreads();
    sq = sh[0] + sh[2] + sh[4] + sh[6];
    sk = sh[1] + sh[3] + sh[5] + sh[7];
    const float rq = QSCALE / fmaxf(sqrtf(sq), 1e-6f);
    const float rk = 1.0f   / fmaxf(sqrtf(sk), 1e-6f);
    qn[(size_t)row * 256 + t] = f2bf(q * rq);
    kn[(size_t)row * 256 + t] = f2bf(k * rk);
}

// ---------------- 32x32 MFMA flash attention: paired q-tiles, uniform blocks ----------------
// Each block processes TWO 64-row q-tiles {31-p, p}: ntiles sums to exactly 17
// for every p -> all 512 blocks identical work, zero tail. 2 blocks/CU, XCD-
// pinned per (b,h) (L&31=bh, 32%8==0). 4 waves = 2 q-bands x 2 k-halves.
// V double-buffered LDS (XOR-swizzled via pre-swizzled global src); K ->regs.

template<bool MASK>
__device__ __forceinline__ void tile32(const unsigned short* Vs, int keybase, int kh,
                                       int l31, int hi, int qg,
                                       const short8 ak0, const short8 ak1, const short8 bq,
                                       f32x16 o[2], float& lpart)
{
    const f32x16 z = {};
    const f32x16 s0 = __builtin_amdgcn_mfma_f32_32x32x16_bf16(ak0, bq, z, 0, 0, 0);
    const f32x16 s1 = __builtin_amdgcn_mfma_f32_32x32x16_bf16(ak1, bq, z, 0, 0, 0);

    float p0[16], p1[16];
    #pragma unroll
    for (int r = 0; r < 16; ++r) {
        float e0 = __builtin_exp2f(s0[r]);
        float e1 = __builtin_exp2f(s1[r]);
        if (MASK) {
            const int kl = keybase + (r & 3) + 8 * (r >> 2) + 4 * hi;
            e0 = (kl > qg) ? 0.0f : e0;
            e1 = (kl + 32 > qg) ? 0.0f : e1;
        }
        p0[r] = e0; p1[r] = e1;
        lpart += e0 + e1;
    }

    short8 pa[4];
    #pragma unroll
    for (int g = 0; g < 4; ++g) {
        const float* pc = (g < 2) ? p0 : p1;
        const int jj = 2 * (g & 1);
        unsigned a0, a1, b0, b1;
        asm("v_cvt_pk_bf16_f32 %0, %1, %2" : "=v"(a0) : "v"(pc[4*jj]),     "v"(pc[4*jj + 1]));
        asm("v_cvt_pk_bf16_f32 %0, %1, %2" : "=v"(b0) : "v"(pc[4*jj + 2]), "v"(pc[4*jj + 3]));
        asm("v_cvt_pk_bf16_f32 %0, %1, %2" : "=v"(a1) : "v"(pc[4*jj + 4]), "v"(pc[4*jj + 5]));
        asm("v_cvt_pk_bf16_f32 %0, %1, %2" : "=v"(b1) : "v"(pc[4*jj + 6]), "v"(pc[4*jj + 7]));
        const uint2v r0 = __builtin_amdgcn_permlane32_swap(a0, a1, false, false);
        const uint2v r1 = __builtin_amdgcn_permlane32_swap(b0, b1, false, false);
        union { short8 s; unsigned u[4]; } pu;
        pu.u[0] = r0[0]; pu.u[1] = r1[0]; pu.u[2] = r0[1]; pu.u[3] = r1[1];
        pa[g] = pu.s;
    }

    #pragma unroll
    for (int g = 0; g < 4; ++g)
        #pragma unroll
        for (int half = 0; half < 2; ++half) {
            const int row = half * 32 + l31;
            const short8 bv = *(const short8*)&Vs[row * 128 + ((64 * kh + 16 * g + 8 * hi) ^ (8 * (row & 7)))];
            o[half] = __builtin_amdgcn_mfma_f32_32x32x16_bf16(pa[g], bv, o[half], 0, 0, 0);
        }
}

__global__ __launch_bounds__(256, 2) void attn64(const unsigned short* __restrict__ qn,
                                                 const unsigned short* __restrict__ kn,
                                                 const unsigned short* __restrict__ vt,
                                                 float* __restrict__ out)
{
    const int L = blockIdx.x;            // 512 flat; L%8 == bh%8 -> XCD-pinned
    const int bh = L & 31;
    const int p  = L >> 5;               // 0..15 -> q-tile pair {31-p, p}
    const int h = bh & 15, b = bh >> 4;

    const int tid = threadIdx.x, w = tid >> 6, lane = tid & 63;
    const int qh = w >> 1, kh = w & 1;
    const int l31 = lane & 31, hi = lane >> 5;

    __shared__ __align__(16) unsigned char smem[32768];  // V dbuf 2x16KB; epilogue overlay

    const int vsub  = lane >> 4;
    const int vslot = lane & 15;

#define STAGEV(kt_, buf_) do {                                                                    \
        const int k0_ = (kt_) * 128;                                                              \
        _Pragma("unroll")                                                                         \
        for (int i = 0; i < 4; ++i) {                                                             \
            const int dh = w * 16 + i * 4 + vsub;                                                 \
            const int so = 8 * (vslot ^ (dh & 7));                                                \
            __builtin_amdgcn_global_load_lds(                                                     \
                (const __attribute__((address_space(1))) unsigned int*)                           \
                    &vt[((size_t)b * DIM + h * DH + dh) * SEQ + k0_ + so],                        \
                (__attribute__((address_space(3))) unsigned int*)(smem + (buf_) * 16384 + (w * 4 + i) * 1024), \
                16, 0, 0);                                                                        \
        }                                                                                         \
    } while (0)

    #pragma unroll 1
    for (int seg = 0; seg < 2; ++seg) {
        const int qt = seg ? p : 31 - p;          // heavy tile first
        const int qband = qt * 64 + qh * 32;
        const int qg = qband + l31;

        const short8 bq = *(const short8*)&qn[((size_t)b * SEQ + qg) * RANK + h * HS + 8 * hi];

        f32x16 o[2] = {};
        float lpart = 0.0f;

        const unsigned short* kbase = kn + ((size_t)b * SEQ + 64 * kh + l31) * RANK + h * HS + 8 * hi;
        short8 ak0 = *(const short8*)kbase;
        short8 ak1 = *(const short8*)(kbase + 32 * RANK);

        const int ntiles = (qt >> 1) + 1;   // tiles of 128 keys

        __syncthreads();                    // smem free (prev segment epilogue done)
        STAGEV(0, 0);
        __syncthreads();

        for (int kt = 0; kt < ntiles - 1; ++kt) {
            STAGEV(kt + 1, (kt + 1) & 1);
            short8 an0 = *(const short8*)(kbase + (size_t)(kt + 1) * 128 * RANK);
            short8 an1 = *(const short8*)(kbase + (size_t)(kt + 1) * 128 * RANK + 32 * RANK);
            __builtin_amdgcn_s_setprio(1);
            tile32<false>((const unsigned short*)(smem + (kt & 1) * 16384),
                          kt * 128 + 64 * kh, kh, l31, hi, qg, ak0, ak1, bq, o, lpart);
            __builtin_amdgcn_s_setprio(0);
            ak0 = an0; ak1 = an1;
            __syncthreads();
        }
        {
            const int kt = ntiles - 1;
            const int wfirst = 128 * kt + 64 * kh;
            const unsigned short* Vs = (const unsigned short*)(smem + (kt & 1) * 16384);
            __builtin_amdgcn_s_setprio(1);
            if (wfirst <= qband + 31) {
                if (wfirst + 63 <= qband)
                    tile32<false>(Vs, wfirst, kh, l31, hi, qg, ak0, ak1, bq, o, lpart);
                else
                    tile32<true>(Vs, wfirst, kh, l31, hi, qg, ak0, ak1, bq, o, lpart);
            }
            __builtin_amdgcn_s_setprio(0);
        }
        __syncthreads();   // V dead; reuse smem for merge

        float* Osm = (float*)smem;              // [2 bands][32 q][64 lane]
        float* Lsm = (float*)(smem + 16384);    // [2 bands][64 lane]
        if (kh == 1) {
            #pragma unroll
            for (int half = 0; half < 2; ++half)
                #pragma unroll
                for (int r = 0; r < 16; ++r) {
                    const int q = (r & 3) + 8 * (r >> 2) + 4 * hi;
                    Osm[(qh * 32 + q) * 64 + half * 32 + l31] = o[half][r];
                }
            Lsm[qh * 64 + lane] = lpart;
        }
        __syncthreads();
        if (kh == 0) {
            float lt = lpart + Lsm[qh * 64 + lane];
            lt += __shfl_xor(lt, 32);
            const float inv = 1.0f / fmaxf(lt, 1e-6f);
            #pragma unroll
            for (int r = 0; r < 16; ++r) {
                const int q = (r & 3) + 8 * (r >> 2) + 4 * hi;
                const float iv = __shfl(inv, q);
                #pragma unroll
                for (int half = 0; half < 2; ++half) {
                    const float val = (o[half][r] + Osm[(qh * 32 + q) * 64 + half * 32 + l31]) * iv;
                    out[((size_t)b * SEQ + qband + q) * DIM + h * DH + half * 32 + l31] = val;
                }
            }
        }
    }
#undef STAGEV
}

extern "C" void kernel_launch(void* const* d_in, const int* in_sizes, int n_in,
                              void* d_out, int out_size, void* d_ws, size_t ws_size,
                              hipStream_t stream)
{
    const float* x   = (const float*)d_in[0];
    // d_in[1] = mask (causal, analytic)
    const float* Wqk = (const float*)d_in[2];
    const float* Wv  = (const float*)d_in[3];
    float* out = (float*)d_out;

    // workspace: xb 8MB | qkb 4MB | vt 8MB | wcat 3MB ; qn/kn overlay xb after GEMM
    unsigned short* xb   = (unsigned short*)d_ws;
    unsigned short* qkb  = xb  + (size_t)MROWS * DIM;
    unsigned short* vt   = qkb + (size_t)MROWS * 512;
    unsigned short* wcat = vt  + (size_t)BATCH * DIM * SEQ;
    unsigned short* qn = xb;
    unsigned short* kn = xb + (size_t)MROWS * RANK;

    conv3<<<5632, 256, 0, stream>>>(x, Wqk, Wv, xb, wcat);
    gemm_mfma<<<dim3(32, 24), 256, 0, stream>>>(xb, wcat, qkb, vt);
    l2norm_split<<<MROWS, 256, 0, stream>>>(qkb, qn, kn);
    attn64<<<dim3(512), 256, 0, stream>>>(qn, kn, vt, out);
}

// Round 8
// 73.287 us; speedup vs baseline: 1.3755x; 1.0025x over previous
//
#include <hip/hip_runtime.h>
#include <math.h>

// Problem constants
#define BATCH 2
#define SEQ   2048
#define DIM   1024
#define RANK  256
#define HEADS 16
#define HS    16
#define DH    64
#define MROWS 4096

#define QSCALE 0.36067376f   // 0.25 * log2(e), folded into normalized q

typedef __attribute__((ext_vector_type(8)))  short    short8;   // 8 bf16
typedef __attribute__((ext_vector_type(4)))  float    f32x4;
typedef __attribute__((ext_vector_type(16))) float    f32x16;
typedef __attribute__((ext_vector_type(2)))  unsigned uint2v;

__device__ __forceinline__ unsigned short f2bf(float f) {
    union { float f; unsigned u; } v; v.f = f;
    return (unsigned short)((v.u + 0x7FFFu + ((v.u >> 16) & 1u)) >> 16);  // RNE
}
__device__ __forceinline__ float bf2f(unsigned short h) {
    union { unsigned u; float f; } v; v.u = ((unsigned)h) << 16;
    return v.f;
}

// ---------------- fused f32 -> bf16 convert for x, Wqk, Wv ----------------
#define XQ   1048576
#define WQKQ 131072
#define WVQ  262144
__global__ __launch_bounds__(256) void conv3(const float* __restrict__ x,
                                             const float* __restrict__ wqk,
                                             const float* __restrict__ wv,
                                             unsigned short* __restrict__ xb,
                                             unsigned short* __restrict__ wcat)
{
    const int i = blockIdx.x * 256 + threadIdx.x;
    const float* src; unsigned short* dst; int j;
    if (i < XQ)              { src = x;   dst = xb;   j = i; }
    else if (i < XQ + WQKQ)  { src = wqk; dst = wcat; j = i - XQ; }
    else                     { src = wv;  dst = wcat + (size_t)4 * WQKQ; j = i - XQ - WQKQ; }
    float4 v = ((const float4*)src)[j];
    ushort4 o; o.x = f2bf(v.x); o.y = f2bf(v.y); o.z = f2bf(v.z); o.w = f2bf(v.w);
    ((ushort4*)dst)[j] = o;
}

// ---------------- MFMA GEMM, 128x64 tile ----------------
__global__ __launch_bounds__(256) void gemm_mfma(const unsigned short* __restrict__ A,
                                                 const unsigned short* __restrict__ W,
                                                 unsigned short* __restrict__ qkb,
                                                 unsigned short* __restrict__ vt)
{
    __shared__ __align__(16) unsigned short Alds[128 * 32];
    __shared__ __align__(16) unsigned short Blds[64 * 32];

    const int tid = threadIdx.x;
    const int w = tid >> 6, lane = tid & 63;
    const int lr = lane & 15, lg = lane >> 4;
    const int wm = w >> 1, wn = w & 1;
    const int bm = blockIdx.x * 128, bn = blockIdx.y * 64;

    const int srow = lane >> 2;
    const int sk   = (lane & 3) * 8;

    f32x4 acc[4][2] = {};

    for (int k0 = 0; k0 < 1024; k0 += 32) {
        __syncthreads();
        #pragma unroll
        for (int q = 0; q < 2; ++q) {
            const int r = (w * 2 + q) * 16 + srow;
            __builtin_amdgcn_global_load_lds(
                (const __attribute__((address_space(1))) unsigned int*)&A[(size_t)(bm + r) * 1024 + k0 + sk],
                (__attribute__((address_space(3))) unsigned int*)&Alds[(w * 2 + q) * 512],
                16, 0, 0);
        }
        __builtin_amdgcn_global_load_lds(
            (const __attribute__((address_space(1))) unsigned int*)&W[(size_t)(bn + w * 16 + srow) * 1024 + k0 + sk],
            (__attribute__((address_space(3))) unsigned int*)&Blds[w * 512],
            16, 0, 0);
        __syncthreads();

        short8 af[4], bfr[2];
        #pragma unroll
        for (int mi = 0; mi < 4; ++mi)
            af[mi] = *(const short8*)&Alds[(wm * 64 + mi * 16 + lr) * 32 + lg * 8];
        #pragma unroll
        for (int ni = 0; ni < 2; ++ni)
            bfr[ni] = *(const short8*)&Blds[(wn * 32 + ni * 16 + lr) * 32 + lg * 8];
        #pragma unroll
        for (int mi = 0; mi < 4; ++mi)
            #pragma unroll
            for (int ni = 0; ni < 2; ++ni)
                acc[mi][ni] = __builtin_amdgcn_mfma_f32_16x16x32_bf16(af[mi], bfr[ni], acc[mi][ni], 0, 0, 0);
    }

    if (bn < 512) {
        #pragma unroll
        for (int mi = 0; mi < 4; ++mi) {
            const int rbase = bm + wm * 64 + mi * 16 + lg * 4;
            #pragma unroll
            for (int ni = 0; ni < 2; ++ni) {
                const int col = bn + wn * 32 + ni * 16 + lr;
                #pragma unroll
                for (int r = 0; r < 4; ++r)
                    qkb[(size_t)(rbase + r) * 512 + col] = f2bf(acc[mi][ni][r]);
            }
        }
    } else {
        const int nb = bn - 512;
        #pragma unroll
        for (int mi = 0; mi < 4; ++mi) {
            const int m = bm + wm * 64 + mi * 16 + lg * 4;
            const int bb = m >> 11, ms = m & 2047;
            #pragma unroll
            for (int ni = 0; ni < 2; ++ni) {
                const int d = nb + wn * 32 + ni * 16 + lr;
                ushort4 pk;
                pk.x = f2bf(acc[mi][ni][0]); pk.y = f2bf(acc[mi][ni][1]);
                pk.z = f2bf(acc[mi][ni][2]); pk.w = f2bf(acc[mi][ni][3]);
                *(ushort4*)&vt[((size_t)bb * DIM + d) * SEQ + ms] = pk;
            }
        }
    }
}

// ---------------- Full-rank L2 normalize; q pre-scaled by QSCALE ----------------
__global__ __launch_bounds__(256) void l2norm_split(const unsigned short* __restrict__ qkb,
                                                    unsigned short* __restrict__ qn,
                                                    unsigned short* __restrict__ kn)
{
    const int row = blockIdx.x;
    const int t = threadIdx.x;
    const unsigned short* p = qkb + (size_t)row * 512;
    float q = bf2f(p[t]);
    float k = bf2f(p[t + 256]);
    float sq = q * q, sk = k * k;
    #pragma unroll
    for (int off = 32; off > 0; off >>= 1) {
        sq += __shfl_down(sq, off);
        sk += __shfl_down(sk, off);
    }
    __shared__ float sh[8];
    const int wid = t >> 6;
    if ((t & 63) == 0) { sh[wid * 2] = sq; sh[wid * 2 + 1] = sk; }
    __syncthreads();
    sq = sh[0] + sh[2] + sh[4] + sh[6];
    sk = sh[1] + sh[3] + sh[5] + sh[7];
    const float rq = QSCALE / fmaxf(sqrtf(sq), 1e-6f);
    const float rk = 1.0f   / fmaxf(sqrtf(sk), 1e-6f);
    qn[(size_t)row * 256 + t] = f2bf(q * rq);
    kn[(size_t)row * 256 + t] = f2bf(k * rk);
}

// ---------------- 32x32 MFMA flash attention: shared-prefix paired q-tiles ----------------
// Block owns TWO q-tiles {31-p, p}; their causal k-ranges are prefix-nested, so
// ONE k-loop (nt0 iters) stages V/K once and computes both segments in the
// overlap. Stage-iterations: 272 -> 200 grid-wide; V/K traffic ~halved.
// 4 waves = 2 q-bands x 2 k-halves; XCD-pinned (L&31=bh). No-max softmax.

template<bool MASK>
__device__ __forceinline__ void tile32(const unsigned short* Vs, int keybase, int kh,
                                       int l31, int hi, int qg,
                                       const short8 ak0, const short8 ak1, const short8 bq,
                                       f32x16 o[2], float& lpart)
{
    const f32x16 z = {};
    const f32x16 s0 = __builtin_amdgcn_mfma_f32_32x32x16_bf16(ak0, bq, z, 0, 0, 0);
    const f32x16 s1 = __builtin_amdgcn_mfma_f32_32x32x16_bf16(ak1, bq, z, 0, 0, 0);

    float p0[16], p1[16];
    #pragma unroll
    for (int r = 0; r < 16; ++r) {
        float e0 = __builtin_exp2f(s0[r]);
        float e1 = __builtin_exp2f(s1[r]);
        if (MASK) {
            const int kl = keybase + (r & 3) + 8 * (r >> 2) + 4 * hi;
            e0 = (kl > qg) ? 0.0f : e0;
            e1 = (kl + 32 > qg) ? 0.0f : e1;
        }
        p0[r] = e0; p1[r] = e1;
        lpart += e0 + e1;
    }

    short8 pa[4];
    #pragma unroll
    for (int g = 0; g < 4; ++g) {
        const float* pc = (g < 2) ? p0 : p1;
        const int jj = 2 * (g & 1);
        unsigned a0, a1, b0, b1;
        asm("v_cvt_pk_bf16_f32 %0, %1, %2" : "=v"(a0) : "v"(pc[4*jj]),     "v"(pc[4*jj + 1]));
        asm("v_cvt_pk_bf16_f32 %0, %1, %2" : "=v"(b0) : "v"(pc[4*jj + 2]), "v"(pc[4*jj + 3]));
        asm("v_cvt_pk_bf16_f32 %0, %1, %2" : "=v"(a1) : "v"(pc[4*jj + 4]), "v"(pc[4*jj + 5]));
        asm("v_cvt_pk_bf16_f32 %0, %1, %2" : "=v"(b1) : "v"(pc[4*jj + 6]), "v"(pc[4*jj + 7]));
        const uint2v r0 = __builtin_amdgcn_permlane32_swap(a0, a1, false, false);
        const uint2v r1 = __builtin_amdgcn_permlane32_swap(b0, b1, false, false);
        union { short8 s; unsigned u[4]; } pu;
        pu.u[0] = r0[0]; pu.u[1] = r1[0]; pu.u[2] = r0[1]; pu.u[3] = r1[1];
        pa[g] = pu.s;
    }

    #pragma unroll
    for (int g = 0; g < 4; ++g)
        #pragma unroll
        for (int half = 0; half < 2; ++half) {
            const int row = half * 32 + l31;
            const short8 bv = *(const short8*)&Vs[row * 128 + ((64 * kh + 16 * g + 8 * hi) ^ (8 * (row & 7)))];
            o[half] = __builtin_amdgcn_mfma_f32_32x32x16_bf16(pa[g], bv, o[half], 0, 0, 0);
        }
}

// dispatch last-tile mask/skip cases for one segment
__device__ __forceinline__ void seg_tile(const unsigned short* Vs, int kb, int kh,
                                         int l31, int hi, int qband, int qg, bool last,
                                         const short8 ak0, const short8 ak1, const short8 bq,
                                         f32x16 o[2], float& lpart)
{
    if (!last) {
        tile32<false>(Vs, kb, kh, l31, hi, qg, ak0, ak1, bq, o, lpart);
    } else if (kb <= qband + 31) {
        if (kb + 63 <= qband)
            tile32<false>(Vs, kb, kh, l31, hi, qg, ak0, ak1, bq, o, lpart);
        else
            tile32<true>(Vs, kb, kh, l31, hi, qg, ak0, ak1, bq, o, lpart);
    }
}

__global__ __launch_bounds__(256, 2) void attn_pair(const unsigned short* __restrict__ qn,
                                                    const unsigned short* __restrict__ kn,
                                                    const unsigned short* __restrict__ vt,
                                                    float* __restrict__ out)
{
    const int L = blockIdx.x;            // 512 flat; L%8 == bh%8 -> XCD-pinned
    const int bh = L & 31;
    const int p  = L >> 5;               // 0..15 -> q-tile pair {31-p, p}
    const int h = bh & 15, b = bh >> 4;

    const int tid = threadIdx.x, w = tid >> 6, lane = tid & 63;
    const int qh = w >> 1, kh = w & 1;
    const int l31 = lane & 31, hi = lane >> 5;

    const int qt0 = 31 - p, qt1 = p;
    const int nt0 = (qt0 >> 1) + 1;      // 9..16
    const int nt1 = (qt1 >> 1) + 1;      // 1..8  (always < nt0)
    const int qband0 = qt0 * 64 + qh * 32, qband1 = qt1 * 64 + qh * 32;
    const int qg0 = qband0 + l31, qg1 = qband1 + l31;

    // V dbuf 2x16KB; epilogue overlay: Os0 16K | Os1 16K | Ls0 .5K | Ls1 .5K
    __shared__ __align__(16) unsigned char smem[33792];

    const short8 bq0 = *(const short8*)&qn[((size_t)b * SEQ + qg0) * RANK + h * HS + 8 * hi];
    const short8 bq1 = *(const short8*)&qn[((size_t)b * SEQ + qg1) * RANK + h * HS + 8 * hi];

    f32x16 o0[2] = {}, o1[2] = {};
    float lp0 = 0.0f, lp1 = 0.0f;

    const unsigned short* kbase = kn + ((size_t)b * SEQ + 64 * kh + l31) * RANK + h * HS + 8 * hi;
    short8 ak0 = *(const short8*)kbase;
    short8 ak1 = *(const short8*)(kbase + 32 * RANK);

    const int vsub  = lane >> 4;
    const int vslot = lane & 15;

#define STAGEV(kt_, buf_) do {                                                                    \
        const int k0_ = (kt_) * 128;                                                              \
        _Pragma("unroll")                                                                         \
        for (int i = 0; i < 4; ++i) {                                                             \
            const int dh = w * 16 + i * 4 + vsub;                                                 \
            const int so = 8 * (vslot ^ (dh & 7));                                                \
            __builtin_amdgcn_global_load_lds(                                                     \
                (const __attribute__((address_space(1))) unsigned int*)                           \
                    &vt[((size_t)b * DIM + h * DH + dh) * SEQ + k0_ + so],                        \
                (__attribute__((address_space(3))) unsigned int*)(smem + (buf_) * 16384 + (w * 4 + i) * 1024), \
                16, 0, 0);                                                                        \
        }                                                                                         \
    } while (0)

    STAGEV(0, 0);
    __syncthreads();

    #pragma unroll 1
    for (int kt = 0; kt < nt0; ++kt) {
        const bool more = (kt + 1 < nt0);
        if (more) STAGEV(kt + 1, (kt + 1) & 1);
        short8 an0 = ak0, an1 = ak1;
        if (more) {
            an0 = *(const short8*)(kbase + (size_t)(kt + 1) * 128 * RANK);
            an1 = *(const short8*)(kbase + (size_t)(kt + 1) * 128 * RANK + 32 * RANK);
        }

        const unsigned short* Vs = (const unsigned short*)(smem + (kt & 1) * 16384);
        const int kb = kt * 128 + 64 * kh;

        __builtin_amdgcn_s_setprio(1);
        // segment 0 (heavy): active all iterations, mask on its last
        seg_tile(Vs, kb, kh, l31, hi, qband0, qg0, kt == nt0 - 1, ak0, ak1, bq0, o0, lp0);
        // segment 1 (light): active while kt < nt1 (prefix of seg0's range)
        if (kt < nt1)
            seg_tile(Vs, kb, kh, l31, hi, qband1, qg1, kt == nt1 - 1, ak0, ak1, bq1, o1, lp1);
        __builtin_amdgcn_s_setprio(0);

        ak0 = an0; ak1 = an1;
        __syncthreads();   // all waves past reads of Vs; staging for kt+1 drained
    }
#undef STAGEV

    // ---- epilogue: merge kh partials for both segments, normalize, store ----
    float* Os0 = (float*)smem;               // [2 bands][32 q][64 lane]
    float* Os1 = (float*)(smem + 16384);
    float* Ls0 = (float*)(smem + 32768);     // [2 bands][64 lane]
    float* Ls1 = (float*)(smem + 33280);

    if (kh == 1) {
        #pragma unroll
        for (int half = 0; half < 2; ++half)
            #pragma unroll
            for (int r = 0; r < 16; ++r) {
                const int q = (r & 3) + 8 * (r >> 2) + 4 * hi;
                Os0[(qh * 32 + q) * 64 + half * 32 + l31] = o0[half][r];
                Os1[(qh * 32 + q) * 64 + half * 32 + l31] = o1[half][r];
            }
        Ls0[qh * 64 + lane] = lp0;
        Ls1[qh * 64 + lane] = lp1;
    }
    __syncthreads();
    if (kh == 0) {
        float lt0 = lp0 + Ls0[qh * 64 + lane];
        float lt1 = lp1 + Ls1[qh * 64 + lane];
        lt0 += __shfl_xor(lt0, 32);
        lt1 += __shfl_xor(lt1, 32);
        const float inv0 = 1.0f / fmaxf(lt0, 1e-6f);
        const float inv1 = 1.0f / fmaxf(lt1, 1e-6f);
        #pragma unroll
        for (int r = 0; r < 16; ++r) {
            const int q = (r & 3) + 8 * (r >> 2) + 4 * hi;
            const float iv0 = __shfl(inv0, q);
            const float iv1 = __shfl(inv1, q);
            #pragma unroll
            for (int half = 0; half < 2; ++half) {
                const float v0 = (o0[half][r] + Os0[(qh * 32 + q) * 64 + half * 32 + l31]) * iv0;
                const float v1 = (o1[half][r] + Os1[(qh * 32 + q) * 64 + half * 32 + l31]) * iv1;
                __builtin_nontemporal_store(v0,
                    &out[((size_t)b * SEQ + qband0 + q) * DIM + h * DH + half * 32 + l31]);
                __builtin_nontemporal_store(v1,
                    &out[((size_t)b * SEQ + qband1 + q) * DIM + h * DH + half * 32 + l31]);
            }
        }
    }
}

extern "C" void kernel_launch(void* const* d_in, const int* in_sizes, int n_in,
                              void* d_out, int out_size, void* d_ws, size_t ws_size,
                              hipStream_t stream)
{
    const float* x   = (const float*)d_in[0];
    // d_in[1] = mask (causal, analytic)
    const float* Wqk = (const float*)d_in[2];
    const float* Wv  = (const float*)d_in[3];
    float* out = (float*)d_out;

    // workspace: xb 8MB | qkb 4MB | vt 8MB | wcat 3MB ; qn/kn overlay xb after GEMM
    unsigned short* xb   = (unsigned short*)d_ws;
    unsigned short* qkb  = xb  + (size_t)MROWS * DIM;
    unsigned short* vt   = qkb + (size_t)MROWS * 512;
    unsigned short* wcat = vt  + (size_t)BATCH * DIM * SEQ;
    unsigned short* qn = xb;
    unsigned short* kn = xb + (size_t)MROWS * RANK;

    conv3<<<5632, 256, 0, stream>>>(x, Wqk, Wv, xb, wcat);
    gemm_mfma<<<dim3(32, 24), 256, 0, stream>>>(xb, wcat, qkb, vt);
    l2norm_split<<<MROWS, 256, 0, stream>>>(qkb, qn, kn);
    attn_pair<<<dim3(512), 256, 0, stream>>>(qn, kn, vt, out);
}